// Round 4
// baseline (69187.878 us; speedup 1.0000x reference)
//
#include <hip/hip_runtime.h>
#include <hip/hip_bf16.h>
#include <stdint.h>

#define T_STEPS 4096
#define BATCH 32
#define IDIM 512
#define HDIM 512
#define CDIM 128

typedef float f32x4 __attribute__((ext_vector_type(4)));
typedef short s16x8 __attribute__((ext_vector_type(8)));
typedef unsigned short u16x4 __attribute__((ext_vector_type(4)));

__device__ __forceinline__ unsigned short f2bf(float f) {
    union { float f; uint32_t u; } v; v.f = f;
    uint32_t r = v.u + 0x7fffu + ((v.u >> 16) & 1u);  // RNE
    return (unsigned short)(r >> 16);
}
__device__ __forceinline__ float bf2f(unsigned short s) {
    union { uint32_t u; float f; } v; v.u = ((uint32_t)s) << 16;
    return v.f;
}

// ---------------------------------------------------------------------------
// Kernel 1: transpose W_hh [H][H] fp32 -> WT[i][j] = W_hh[j][i]
// ---------------------------------------------------------------------------
__global__ void transpose_whh(const float* __restrict__ W, float* __restrict__ WT) {
    __shared__ float tile[32][33];
    const int tx = threadIdx.x, ty = threadIdx.y;
    const int bx = blockIdx.x, by = blockIdx.y;
    int x = bx * 32 + tx;
    #pragma unroll
    for (int k = 0; k < 32; k += 8) {
        int y = by * 32 + ty + k;
        tile[ty + k][tx] = W[(size_t)y * HDIM + x];
    }
    __syncthreads();
    #pragma unroll
    for (int k = 0; k < 32; k += 8) {
        int i_out = bx * 32 + ty + k;
        int j_out = by * 32 + tx;
        WT[(size_t)i_out * HDIM + j_out] = tile[tx][ty + k];
    }
}

// ---------------------------------------------------------------------------
// Kernel 2: A[m][n] = bf16( X[m][:] . Wih[n][:] + bih[n] + bhh[n] )
// ---------------------------------------------------------------------------
__global__ __launch_bounds__(256) void xih_gemm(
    const float* __restrict__ X,    // [M][K] fp32
    const float* __restrict__ Wih,  // [N][K] fp32
    const float* __restrict__ bih,
    const float* __restrict__ bhh,
    unsigned short* __restrict__ A) // [M][N] bf16 bits
{
    __shared__ __align__(16) unsigned short As[128][40];
    __shared__ __align__(16) unsigned short Bs[128][40];

    const int tid  = threadIdx.x;
    const int lane = tid & 63;
    const int wave = tid >> 6;
    const int wr = wave >> 1, wc = wave & 1;
    const int row0 = blockIdx.y * 128;
    const int col0 = blockIdx.x * 128;
    const int l16 = lane & 15, lhi = lane >> 4;

    const int lr = tid >> 3;
    const int kf = tid & 7;

    f32x4 acc[4][4] = {};

    for (int k0 = 0; k0 < IDIM; k0 += 32) {
        #pragma unroll
        for (int rr = 0; rr < 128; rr += 32) {
            int r = lr + rr;
            float4 xv = *(const float4*)&X[(size_t)(row0 + r) * IDIM + k0 + kf * 4];
            float4 wv = *(const float4*)&Wih[(size_t)(col0 + r) * IDIM + k0 + kf * 4];
            u16x4 xq, wq;
            xq.x = f2bf(xv.x); xq.y = f2bf(xv.y); xq.z = f2bf(xv.z); xq.w = f2bf(xv.w);
            wq.x = f2bf(wv.x); wq.y = f2bf(wv.y); wq.z = f2bf(wv.z); wq.w = f2bf(wv.w);
            *(u16x4*)&As[r][kf * 4] = xq;
            *(u16x4*)&Bs[r][kf * 4] = wq;
        }
        __syncthreads();

        s16x8 af[4], bfr[4];
        #pragma unroll
        for (int mi = 0; mi < 4; ++mi)
            af[mi] = *(const s16x8*)&As[wr * 64 + mi * 16 + l16][lhi * 8];
        #pragma unroll
        for (int ni = 0; ni < 4; ++ni)
            bfr[ni] = *(const s16x8*)&Bs[wc * 64 + ni * 16 + l16][lhi * 8];
        #pragma unroll
        for (int mi = 0; mi < 4; ++mi)
            #pragma unroll
            for (int ni = 0; ni < 4; ++ni)
                acc[mi][ni] = __builtin_amdgcn_mfma_f32_16x16x32_bf16(
                    af[mi], bfr[ni], acc[mi][ni], 0, 0, 0);
        __syncthreads();
    }

    #pragma unroll
    for (int ni = 0; ni < 4; ++ni) {
        int col = col0 + wc * 64 + ni * 16 + l16;
        float bias = bih[col] + bhh[col];
        #pragma unroll
        for (int mi = 0; mi < 4; ++mi) {
            int rowb = row0 + wr * 64 + mi * 16 + lhi * 4;
            #pragma unroll
            for (int r = 0; r < 4; ++r)
                A[(size_t)(rowb + r) * HDIM + col] = f2bf(acc[mi][ni][r] + bias);
        }
    }
}

// ---------------------------------------------------------------------------
// Kernel 3: persistent per-batch recurrence, W_hh^T RESIDENT IN VGPRs.
// 32 workgroups (one per batch), 512 threads: thread = (4 cols) x (K-quarter).
// Per-thread W slice: 128 k-rows x 4 cols = 128 f32x4 = 128 VGPRs, loaded once.
// h in LDS (reads are wave-uniform broadcasts -> conflict-free).
// ---------------------------------------------------------------------------
__global__ __launch_bounds__(512, 2) void rnn_scan(
    const unsigned short* __restrict__ A,  // [tc][BATCH][HDIM] bf16 bits
    const float* __restrict__ WT,          // [HDIM][HDIM]: WT[i][j] = Whh[j][i]
    const float* __restrict__ Wfc,         // [CDIM][HDIM]
    const float* __restrict__ bfc,         // [CDIM]
    float* __restrict__ out,               // [BATCH][CDIM]
    float* __restrict__ hstate,            // [BATCH][HDIM]
    int tc, int do_fc)
{
    __shared__ __align__(16) float hs[HDIM];
    __shared__ __align__(16) float ps[4][HDIM];

    const int b   = blockIdx.x;
    const int tid = threadIdx.x;
    const int j4  = tid & 127;     // column group
    const int q   = tid >> 7;      // K quarter 0..3
    const int c4  = j4 * 4;        // first of 4 owned columns
    const int iq0 = q * 128;       // K range start

    // ---- load this thread's W slice into registers (static indices) ----
    f32x4 w[32][4];
    {
        const float* wp0 = WT + (size_t)iq0 * HDIM + c4;
        #pragma unroll
        for (int i = 0; i < 32; ++i)
            #pragma unroll
            for (int r = 0; r < 4; ++r)
                w[i][r] = *(const f32x4*)(wp0 + (size_t)(i * 4 + r) * HDIM);
    }

    hs[tid] = hstate[b * HDIM + tid];
    __syncthreads();

    const unsigned short* Ab = A + (size_t)b * HDIM + tid;

    // prefetch first a_t
    float a_cur = bf2f(Ab[0]);

    for (int t = 0; t < tc; ++t) {
        // prefetch next step's additive term (hide global latency under FMAs)
        int tn = t + 1 < tc ? t + 1 : t;
        float a_next = bf2f(Ab[(size_t)tn * (BATCH * HDIM)]);

        f32x4 acc = {};
        #pragma unroll
        for (int i = 0; i < 32; ++i) {
            f32x4 hv = *(const f32x4*)&hs[iq0 + i * 4];
            acc += w[i][0] * hv.x;
            acc += w[i][1] * hv.y;
            acc += w[i][2] * hv.z;
            acc += w[i][3] * hv.w;
        }
        *(f32x4*)&ps[q][c4] = acc;
        __syncthreads();                    // all hs reads + ps writes done
        float v = ps[0][tid] + ps[1][tid] + ps[2][tid] + ps[3][tid] + a_cur;
        hs[tid] = fmaxf(v, 0.f);
        a_cur = a_next;
        __syncthreads();                    // hs update visible for next step
    }

    hstate[b * HDIM + tid] = hs[tid];

    if (do_fc) {
        const int c  = tid & (CDIM - 1);
        const int fq = tid >> 7;           // i-quarter
        float facc = 0.f;
        #pragma unroll 4
        for (int i = fq * 128; i < fq * 128 + 128; i += 4) {
            float4 hv = *(const float4*)&hs[i];
            float4 wv = *(const float4*)&Wfc[(size_t)c * HDIM + i];
            facc += hv.x * wv.x + hv.y * wv.y + hv.z * wv.z + hv.w * wv.w;
        }
        __syncthreads();
        ps[fq][c] = facc;
        __syncthreads();
        if (fq == 0)
            out[b * CDIM + c] = ps[0][c] + ps[1][c] + ps[2][c] + ps[3][c] + bfc[c];
    }
}

// ---------------------------------------------------------------------------
extern "C" void kernel_launch(void* const* d_in, const int* in_sizes, int n_in,
                              void* d_out, int out_size, void* d_ws, size_t ws_size,
                              hipStream_t stream) {
    const float* x   = (const float*)d_in[0];  // [T][B][I]
    const float* h0  = (const float*)d_in[1];  // [B][H]
    const float* Wih = (const float*)d_in[2];  // [H][I]
    const float* bih = (const float*)d_in[3];  // [H]
    const float* Whh = (const float*)d_in[4];  // [H][H]
    const float* bhh = (const float*)d_in[5];  // [H]
    const float* Wfc = (const float*)d_in[6];  // [C][H]
    const float* bfc = (const float*)d_in[7];  // [C]

    float* out  = (float*)d_out;               // [B][C]
    float* hfin = out + BATCH * CDIM;          // [B][H]

    float* WT = (float*)d_ws;                                  // 1 MB
    const size_t wt_bytes = (size_t)HDIM * HDIM * sizeof(float);
    unsigned short* Abuf = (unsigned short*)((char*)d_ws + wt_bytes);

    const size_t per_t = (size_t)BATCH * HDIM * sizeof(unsigned short); // 32 KB
    size_t avail = ws_size > wt_bytes ? ws_size - wt_bytes : 0;
    long long tcl = (long long)(avail / per_t);
    if (tcl > T_STEPS) tcl = T_STEPS;
    int TC = (int)(tcl & ~3LL);
    if (TC < 4) TC = 4;

    transpose_whh<<<dim3(16, 16), dim3(32, 8), 0, stream>>>(Whh, WT);
    hipMemcpyAsync(hfin, h0, (size_t)BATCH * HDIM * sizeof(float),
                   hipMemcpyDeviceToDevice, stream);

    for (int t0 = 0; t0 < T_STEPS; t0 += TC) {
        int tc = T_STEPS - t0 < TC ? T_STEPS - t0 : TC;
        xih_gemm<<<dim3(4, tc * BATCH / 128), 256, 0, stream>>>(
            x + (size_t)t0 * BATCH * IDIM, Wih, bih, bhh, Abuf);
        int do_fc = (t0 + tc >= T_STEPS) ? 1 : 0;
        rnn_scan<<<BATCH, 512, 0, stream>>>(Abuf, WT, Wfc, bfc, out, hfin, tc, do_fc);
    }
}

// Round 6
// 18216.058 us; speedup vs baseline: 3.7982x; 3.7982x over previous
//
#include <hip/hip_runtime.h>
#include <hip/hip_bf16.h>
#include <stdint.h>

#define T_STEPS 4096
#define BATCH 32
#define IDIM 512
#define HDIM 512
#define CDIM 128
#define NSPLIT 4      // blocks per batch (output-dim split)
#define CSLICE 128    // HDIM / NSPLIT

typedef float f32x4 __attribute__((ext_vector_type(4)));
typedef short s16x8 __attribute__((ext_vector_type(8)));
typedef unsigned short u16x4 __attribute__((ext_vector_type(4)));

__device__ __forceinline__ unsigned short f2bf(float f) {
    union { float f; uint32_t u; } v; v.f = f;
    uint32_t r = v.u + 0x7fffu + ((v.u >> 16) & 1u);  // RNE
    return (unsigned short)(r >> 16);
}
__device__ __forceinline__ float bf2f(unsigned short s) {
    union { uint32_t u; float f; } v; v.u = ((uint32_t)s) << 16;
    return v.f;
}

// ---------------------------------------------------------------------------
// Kernel 1: A[m][n] = bf16( X[m][:] . Wih[n][:] + bih[n] + bhh[n] )
// (unchanged from R1 — ~3% of runtime)
// ---------------------------------------------------------------------------
__global__ __launch_bounds__(256) void xih_gemm(
    const float* __restrict__ X,    // [M][K] fp32
    const float* __restrict__ Wih,  // [N][K] fp32
    const float* __restrict__ bih,
    const float* __restrict__ bhh,
    unsigned short* __restrict__ A) // [M][N] bf16 bits
{
    __shared__ __align__(16) unsigned short As[128][40];
    __shared__ __align__(16) unsigned short Bs[128][40];

    const int tid  = threadIdx.x;
    const int lane = tid & 63;
    const int wave = tid >> 6;
    const int wr = wave >> 1, wc = wave & 1;
    const int row0 = blockIdx.y * 128;
    const int col0 = blockIdx.x * 128;
    const int l16 = lane & 15, lhi = lane >> 4;

    const int lr = tid >> 3;
    const int kf = tid & 7;

    f32x4 acc[4][4] = {};

    for (int k0 = 0; k0 < IDIM; k0 += 32) {
        #pragma unroll
        for (int rr = 0; rr < 128; rr += 32) {
            int r = lr + rr;
            float4 xv = *(const float4*)&X[(size_t)(row0 + r) * IDIM + k0 + kf * 4];
            float4 wv = *(const float4*)&Wih[(size_t)(col0 + r) * IDIM + k0 + kf * 4];
            u16x4 xq, wq;
            xq.x = f2bf(xv.x); xq.y = f2bf(xv.y); xq.z = f2bf(xv.z); xq.w = f2bf(xv.w);
            wq.x = f2bf(wv.x); wq.y = f2bf(wv.y); wq.z = f2bf(wv.z); wq.w = f2bf(wv.w);
            *(u16x4*)&As[r][kf * 4] = xq;
            *(u16x4*)&Bs[r][kf * 4] = wq;
        }
        __syncthreads();

        s16x8 af[4], bfr[4];
        #pragma unroll
        for (int mi = 0; mi < 4; ++mi)
            af[mi] = *(const s16x8*)&As[wr * 64 + mi * 16 + l16][lhi * 8];
        #pragma unroll
        for (int ni = 0; ni < 4; ++ni)
            bfr[ni] = *(const s16x8*)&Bs[wc * 64 + ni * 16 + l16][lhi * 8];
        #pragma unroll
        for (int mi = 0; mi < 4; ++mi)
            #pragma unroll
            for (int ni = 0; ni < 4; ++ni)
                acc[mi][ni] = __builtin_amdgcn_mfma_f32_16x16x32_bf16(
                    af[mi], bfr[ni], acc[mi][ni], 0, 0, 0);
        __syncthreads();
    }

    #pragma unroll
    for (int ni = 0; ni < 4; ++ni) {
        int col = col0 + wc * 64 + ni * 16 + l16;
        float bias = bih[col] + bhh[col];
        #pragma unroll
        for (int mi = 0; mi < 4; ++mi) {
            int rowb = row0 + wr * 64 + mi * 16 + lhi * 4;
            #pragma unroll
            for (int r = 0; r < 4; ++r)
                A[(size_t)(rowb + r) * HDIM + col] = f2bf(acc[mi][ni][r] + bias);
        }
    }
}

// ---------------------------------------------------------------------------
// Kernel 2: recurrence, output-split 4 ways per batch -> 128 blocks (1/CU).
// Block (b, j) computes h-slice [j*128, j*128+128) each step.
// Thread (c = tid&127, q = tid>>7): owns W_hh[j*128+c][q*128 .. q*128+127]
// in 32 f32x4 VGPRs (128 regs — fits under 256-cap, no spill).
// Cross-block h exchange: double-buffered hx in d_ws via agent-scope
// (device-coherent) atomics + per-block monotonic release flags.
// ---------------------------------------------------------------------------
__global__ __launch_bounds__(512, 2) void rnn_scan(
    const unsigned short* __restrict__ A,  // [tc][BATCH][HDIM] bf16 bits
    const float* __restrict__ Whh,         // [HDIM][HDIM] row-major
    const float* __restrict__ Wfc,         // [CDIM][HDIM]
    const float* __restrict__ bfc,         // [CDIM]
    float* __restrict__ hx,                // [2][BATCH][HDIM] exchange bufs
    int* __restrict__ flags,               // [BATCH][NSPLIT] monotonic step flags
    float* __restrict__ out,               // [BATCH][CDIM]
    float* __restrict__ hfin,              // [BATCH][HDIM] (2nd output)
    int tc, int t0, int do_fc)
{
    __shared__ __align__(16) float hs[HDIM];
    __shared__ __align__(16) float ps[NSPLIT][CSLICE];

    const int tid = threadIdx.x;
    const int b = blockIdx.x >> 2;       // batch
    const int j = blockIdx.x & 3;        // output-slice index
    const int c = tid & (CSLICE - 1);    // local output col
    const int q = tid >> 7;              // k quarter 0..3
    const int cg = j * CSLICE + c;       // global output col

    // ---- W slice resident in VGPRs: 32 f32x4 (static indices, no spill) ----
    f32x4 w[32];
    {
        const float* wr = Whh + (size_t)cg * HDIM + q * 128;
        #pragma unroll
        for (int i = 0; i < 32; ++i)
            w[i] = *(const f32x4*)(wr + i * 4);
    }

    const unsigned short* Ab = A + (size_t)b * HDIM + j * CSLICE;
    int* myflags = flags + b * NSPLIT;

    for (int t = 0; t < tc; ++t) {
        const int gs = t0 + t;           // global step: consume h_gs, make h_{gs+1}

        // prefetch this step's additive term for reducer threads
        float a_t = 0.f;
        if (tid < CSLICE)
            a_t = bf2f(Ab[(size_t)t * (BATCH * HDIM) + tid]);

        // ---- wait until all 4 slices of h_gs are published ----
        if (tid < NSPLIT) {
            while (__hip_atomic_load(&myflags[tid], __ATOMIC_ACQUIRE,
                                     __HIP_MEMORY_SCOPE_AGENT) < gs)
                __builtin_amdgcn_s_sleep(1);
        }
        __syncthreads();

        // ---- load h_gs (agent scope: bypasses stale per-XCD L2) -> LDS ----
        const float* hb = hx + (size_t)(gs & 1) * (BATCH * HDIM) + b * HDIM;
        hs[tid] = __hip_atomic_load(&hb[tid], __ATOMIC_RELAXED,
                                    __HIP_MEMORY_SCOPE_AGENT);
        __syncthreads();

        // ---- compute partial dot: 128 MACs from VGPR W x LDS-broadcast h ----
        f32x4 acc = {};
        #pragma unroll
        for (int i = 0; i < 32; ++i) {
            f32x4 hv = *(const f32x4*)&hs[q * 128 + i * 4];
            acc += w[i] * hv;
        }
        ps[q][c] = acc.x + acc.y + acc.z + acc.w;
        __syncthreads();

        // ---- reduce 4 partials, relu, publish slice of h_{gs+1} ----
        if (tid < CSLICE) {
            float v = ps[0][tid] + ps[1][tid] + ps[2][tid] + ps[3][tid] + a_t;
            v = fmaxf(v, 0.f);
            float* ho = hx + (size_t)((gs + 1) & 1) * (BATCH * HDIM)
                        + b * HDIM + j * CSLICE + tid;
            __hip_atomic_store(ho, v, __ATOMIC_RELAXED, __HIP_MEMORY_SCOPE_AGENT);
            if (do_fc && t == tc - 1)
                hfin[b * HDIM + j * CSLICE + tid] = v;   // plain store, kernel-end flush
        }
        __syncthreads();   // emits s_waitcnt vmcnt(0) for all threads, then barrier

        if (tid == 0)
            __hip_atomic_store(&myflags[j], gs + 1, __ATOMIC_RELEASE,
                               __HIP_MEMORY_SCOPE_AGENT);
    }

    // ---- fused FC on final h (block j==0 of each batch) ----
    if (do_fc && j == 0) {
        const int target = t0 + tc;
        if (tid < NSPLIT) {
            while (__hip_atomic_load(&myflags[tid], __ATOMIC_ACQUIRE,
                                     __HIP_MEMORY_SCOPE_AGENT) < target)
                __builtin_amdgcn_s_sleep(1);
        }
        __syncthreads();
        const float* hb = hx + (size_t)(target & 1) * (BATCH * HDIM) + b * HDIM;
        hs[tid] = __hip_atomic_load(&hb[tid], __ATOMIC_RELAXED,
                                    __HIP_MEMORY_SCOPE_AGENT);
        __syncthreads();

        // out[b][c] = bfc[c] + sum_k Wfc[c][k] * h[k]   (c = 0..127)
        float facc = 0.f;
        const float* wf = Wfc + (size_t)c * HDIM + q * 128;
        #pragma unroll
        for (int i = 0; i < 32; ++i) {
            f32x4 wv = *(const f32x4*)(wf + i * 4);
            f32x4 hv = *(const f32x4*)&hs[q * 128 + i * 4];
            f32x4 p = wv * hv;
            facc += p.x + p.y + p.z + p.w;
        }
        ps[q][c] = facc;
        __syncthreads();
        if (tid < CSLICE)
            out[b * CDIM + tid] = ps[0][tid] + ps[1][tid] + ps[2][tid]
                                + ps[3][tid] + bfc[tid];
    }
}

// ---------------------------------------------------------------------------
extern "C" void kernel_launch(void* const* d_in, const int* in_sizes, int n_in,
                              void* d_out, int out_size, void* d_ws, size_t ws_size,
                              hipStream_t stream) {
    const float* x   = (const float*)d_in[0];  // [T][B][I]
    const float* h0  = (const float*)d_in[1];  // [B][H]
    const float* Wih = (const float*)d_in[2];  // [H][I]
    const float* bih = (const float*)d_in[3];  // [H]
    const float* Whh = (const float*)d_in[4];  // [H][H]
    const float* bhh = (const float*)d_in[5];  // [H]
    const float* Wfc = (const float*)d_in[6];  // [C][H]
    const float* bfc = (const float*)d_in[7];  // [C]

    float* out  = (float*)d_out;               // [B][C]
    float* hfin = out + BATCH * CDIM;          // [B][H]

    // d_ws layout: [hx: 2*B*H f32][flags: B*NSPLIT int, padded][Abuf: rest]
    float* hx = (float*)d_ws;
    const size_t hx_bytes = (size_t)2 * BATCH * HDIM * sizeof(float);   // 128 KB
    int* flags = (int*)((char*)d_ws + hx_bytes);
    const size_t fl_bytes = 512;                                        // >= B*NSPLIT*4
    unsigned short* Abuf = (unsigned short*)((char*)d_ws + hx_bytes + fl_bytes);

    const size_t per_t = (size_t)BATCH * HDIM * sizeof(unsigned short); // 32 KB
    size_t head = hx_bytes + fl_bytes;
    size_t avail = ws_size > head ? ws_size - head : 0;
    long long tcl = (long long)(avail / per_t);
    if (tcl > T_STEPS) tcl = T_STEPS;
    int TC = (int)(tcl & ~3LL);
    if (TC < 4) TC = 4;

    // flags must start at 0 each launch (monotonic within launch)
    hipMemsetAsync(flags, 0, fl_bytes, stream);
    // seed h_0 into exchange buffer parity 0
    hipMemcpyAsync(hx, h0, (size_t)BATCH * HDIM * sizeof(float),
                   hipMemcpyDeviceToDevice, stream);

    for (int t0 = 0; t0 < T_STEPS; t0 += TC) {
        int tc = T_STEPS - t0 < TC ? T_STEPS - t0 : TC;
        xih_gemm<<<dim3(4, tc * BATCH / 128), 256, 0, stream>>>(
            x + (size_t)t0 * BATCH * IDIM, Wih, bih, bhh, Abuf);
        int do_fc = (t0 + tc >= T_STEPS) ? 1 : 0;
        rnn_scan<<<BATCH * NSPLIT, 512, 0, stream>>>(
            Abuf, Whh, Wfc, bfc, hx, flags, out, hfin, tc, t0, do_fc);
    }
}

// Round 7
// 18129.099 us; speedup vs baseline: 3.8164x; 1.0048x over previous
//
#include <hip/hip_runtime.h>
#include <hip/hip_bf16.h>
#include <stdint.h>

#define T_STEPS 4096
#define BATCH 32
#define IDIM 512
#define HDIM 512
#define CDIM 128
#define NSPLIT 4      // blocks per batch (output-dim split)
#define CSLICE 128    // HDIM / NSPLIT
#define QPAD 132      // padded quarter stride in LDS (conflict-free quad reads)

typedef float f32x4 __attribute__((ext_vector_type(4)));
typedef short s16x8 __attribute__((ext_vector_type(8)));
typedef unsigned short u16x4 __attribute__((ext_vector_type(4)));

__device__ __forceinline__ unsigned short f2bf(float f) {
    union { float f; uint32_t u; } v; v.f = f;
    uint32_t r = v.u + 0x7fffu + ((v.u >> 16) & 1u);  // RNE
    return (unsigned short)(r >> 16);
}
__device__ __forceinline__ float bf2f(unsigned short s) {
    union { uint32_t u; float f; } v; v.u = ((uint32_t)s) << 16;
    return v.f;
}

// ---------------------------------------------------------------------------
// Kernel 1: A[m][n] = bf16( X[m][:] . Wih[n][:] + bih[n] + bhh[n] )
// ---------------------------------------------------------------------------
__global__ __launch_bounds__(256) void xih_gemm(
    const float* __restrict__ X,    // [M][K] fp32
    const float* __restrict__ Wih,  // [N][K] fp32
    const float* __restrict__ bih,
    const float* __restrict__ bhh,
    unsigned short* __restrict__ A) // [M][N] bf16 bits
{
    __shared__ __align__(16) unsigned short As[128][40];
    __shared__ __align__(16) unsigned short Bs[128][40];

    const int tid  = threadIdx.x;
    const int lane = tid & 63;
    const int wave = tid >> 6;
    const int wr = wave >> 1, wc = wave & 1;
    const int row0 = blockIdx.y * 128;
    const int col0 = blockIdx.x * 128;
    const int l16 = lane & 15, lhi = lane >> 4;

    const int lr = tid >> 3;
    const int kf = tid & 7;

    f32x4 acc[4][4] = {};

    for (int k0 = 0; k0 < IDIM; k0 += 32) {
        #pragma unroll
        for (int rr = 0; rr < 128; rr += 32) {
            int r = lr + rr;
            float4 xv = *(const float4*)&X[(size_t)(row0 + r) * IDIM + k0 + kf * 4];
            float4 wv = *(const float4*)&Wih[(size_t)(col0 + r) * IDIM + k0 + kf * 4];
            u16x4 xq, wq;
            xq.x = f2bf(xv.x); xq.y = f2bf(xv.y); xq.z = f2bf(xv.z); xq.w = f2bf(xv.w);
            wq.x = f2bf(wv.x); wq.y = f2bf(wv.y); wq.z = f2bf(wv.z); wq.w = f2bf(wv.w);
            *(u16x4*)&As[r][kf * 4] = xq;
            *(u16x4*)&Bs[r][kf * 4] = wq;
        }
        __syncthreads();

        s16x8 af[4], bfr[4];
        #pragma unroll
        for (int mi = 0; mi < 4; ++mi)
            af[mi] = *(const s16x8*)&As[wr * 64 + mi * 16 + l16][lhi * 8];
        #pragma unroll
        for (int ni = 0; ni < 4; ++ni)
            bfr[ni] = *(const s16x8*)&Bs[wc * 64 + ni * 16 + l16][lhi * 8];
        #pragma unroll
        for (int mi = 0; mi < 4; ++mi)
            #pragma unroll
            for (int ni = 0; ni < 4; ++ni)
                acc[mi][ni] = __builtin_amdgcn_mfma_f32_16x16x32_bf16(
                    af[mi], bfr[ni], acc[mi][ni], 0, 0, 0);
        __syncthreads();
    }

    #pragma unroll
    for (int ni = 0; ni < 4; ++ni) {
        int col = col0 + wc * 64 + ni * 16 + l16;
        float bias = bih[col] + bhh[col];
        #pragma unroll
        for (int mi = 0; mi < 4; ++mi) {
            int rowb = row0 + wr * 64 + mi * 16 + lhi * 4;
            #pragma unroll
            for (int r = 0; r < 4; ++r)
                A[(size_t)(rowb + r) * HDIM + col] = f2bf(acc[mi][ni][r] + bias);
        }
    }
}

// ---------------------------------------------------------------------------
// Kernel 2: recurrence, 128 blocks (1/CU), W truly VGPR-resident.
// Thread quad mapping: c = tid>>2 (local col), q = tid&3 (k-quarter).
// W slice: W_hh[j*128+c][q*128 .. +127] = 32 f32x4 = 128 VGPRs.
// Partial reduce via 2x shfl_xor within the quad (no LDS ps, one less barrier).
// h staged in LDS with 132-float quarter stride (bank-conflict-free).
// Cross-block exchange: double-buffered hx + per-slice monotonic flags
// (agent scope — coherent across XCDs).
// ---------------------------------------------------------------------------
__global__ __launch_bounds__(512, 1) void rnn_scan(
    const unsigned short* __restrict__ A,  // [tc][BATCH][HDIM] bf16 bits
    const float* __restrict__ Whh,         // [HDIM][HDIM] row-major
    const float* __restrict__ Wfc,         // [CDIM][HDIM]
    const float* __restrict__ bfc,         // [CDIM]
    float* __restrict__ hx,                // [2][BATCH][HDIM] exchange bufs
    int* __restrict__ flags,               // [BATCH][NSPLIT] monotonic step flags
    float* __restrict__ out,               // [BATCH][CDIM]
    float* __restrict__ hfin,              // [BATCH][HDIM] (2nd output)
    int tc, int t0, int do_fc)
{
    __shared__ __align__(16) float hs[4 * QPAD];   // padded h staging

    const int tid = threadIdx.x;
    const int b = blockIdx.x >> 2;       // batch
    const int j = blockIdx.x & 3;        // output-slice index
    const int c = tid >> 2;              // local output col 0..127
    const int q = tid & 3;               // k-quarter 0..3
    const int cg = j * CSLICE + c;       // global output col
    const int wq = (tid >> 7) * QPAD + (tid & 127);  // this thread's LDS write slot

    // ---- W slice resident in VGPRs: 32 f32x4 (static indices) ----
    f32x4 w[32];
    {
        const float* wr = Whh + (size_t)cg * HDIM + q * 128;
        #pragma unroll
        for (int i = 0; i < 32; ++i)
            w[i] = *(const f32x4*)(wr + i * 4);
    }

    const unsigned short* Ab = A + (size_t)b * HDIM + cg;
    int* myflags = flags + b * NSPLIT;

    for (int t = 0; t < tc; ++t) {
        const int gs = t0 + t;           // consume h_gs, produce h_{gs+1}

        // prefetch additive term (same addr across quad -> broadcast)
        float a_t = bf2f(Ab[(size_t)t * (BATCH * HDIM)]);

        // ---- wait until all 4 slices of h_gs are published ----
        if (tid < NSPLIT) {
            while (__hip_atomic_load(&myflags[tid], __ATOMIC_ACQUIRE,
                                     __HIP_MEMORY_SCOPE_AGENT) < gs)
                __builtin_amdgcn_s_sleep(1);
        }
        __syncthreads();

        // ---- load h_gs (agent scope) -> padded LDS ----
        const float* hb = hx + (size_t)(gs & 1) * (BATCH * HDIM) + b * HDIM;
        hs[wq] = __hip_atomic_load(&hb[tid], __ATOMIC_RELAXED,
                                   __HIP_MEMORY_SCOPE_AGENT);
        __syncthreads();

        // ---- partial dot from VGPR W x LDS h-quarter ----
        f32x4 acc = {};
        const float* hq = &hs[q * QPAD];
        #pragma unroll
        for (int i = 0; i < 32; ++i) {
            f32x4 hv = *(const f32x4*)(hq + i * 4);
            acc += w[i] * hv;
        }
        float v = acc.x + acc.y + acc.z + acc.w;
        // quad butterfly: sum the 4 k-partials
        v += __shfl_xor(v, 1);
        v += __shfl_xor(v, 2);
        v = fmaxf(v + a_t, 0.f);

        // ---- publish slice of h_{gs+1} (q==0 lanes: 1 col each) ----
        if (q == 0) {
            float* ho = hx + (size_t)((gs + 1) & 1) * (BATCH * HDIM)
                        + b * HDIM + cg;
            __hip_atomic_store(ho, v, __ATOMIC_RELAXED, __HIP_MEMORY_SCOPE_AGENT);
            if (do_fc && t == tc - 1)
                hfin[b * HDIM + cg] = v;   // plain store, flushed at kernel end
        }
        __syncthreads();   // waits vmcnt(0) for all threads, then barrier

        if (tid == 0)
            __hip_atomic_store(&myflags[j], gs + 1, __ATOMIC_RELEASE,
                               __HIP_MEMORY_SCOPE_AGENT);
    }

    // ---- fused FC on final h (block j==0 of each batch) ----
    if (do_fc && j == 0) {
        const int target = t0 + tc;
        if (tid < NSPLIT) {
            while (__hip_atomic_load(&myflags[tid], __ATOMIC_ACQUIRE,
                                     __HIP_MEMORY_SCOPE_AGENT) < target)
                __builtin_amdgcn_s_sleep(1);
        }
        __syncthreads();
        const float* hb = hx + (size_t)(target & 1) * (BATCH * HDIM) + b * HDIM;
        hs[wq] = __hip_atomic_load(&hb[tid], __ATOMIC_RELAXED,
                                   __HIP_MEMORY_SCOPE_AGENT);
        __syncthreads();

        // out[b][c] = bfc[c] + sum_k Wfc[c][k] * h[k]; c = tid>>2, q = tid&3
        float facc = 0.f;
        const float* wf = Wfc + (size_t)c * HDIM + q * 128;
        const float* hq = &hs[q * QPAD];
        #pragma unroll
        for (int i = 0; i < 32; ++i) {
            f32x4 wv = *(const f32x4*)(wf + i * 4);
            f32x4 hv = *(const f32x4*)(hq + i * 4);
            f32x4 p = wv * hv;
            facc += p.x + p.y + p.z + p.w;
        }
        facc += __shfl_xor(facc, 1);
        facc += __shfl_xor(facc, 2);
        if (q == 0)
            out[b * CDIM + c] = facc + bfc[c];
    }
}

// ---------------------------------------------------------------------------
extern "C" void kernel_launch(void* const* d_in, const int* in_sizes, int n_in,
                              void* d_out, int out_size, void* d_ws, size_t ws_size,
                              hipStream_t stream) {
    const float* x   = (const float*)d_in[0];  // [T][B][I]
    const float* h0  = (const float*)d_in[1];  // [B][H]
    const float* Wih = (const float*)d_in[2];  // [H][I]
    const float* bih = (const float*)d_in[3];  // [H]
    const float* Whh = (const float*)d_in[4];  // [H][H]
    const float* bhh = (const float*)d_in[5];  // [H]
    const float* Wfc = (const float*)d_in[6];  // [C][H]
    const float* bfc = (const float*)d_in[7];  // [C]

    float* out  = (float*)d_out;               // [B][C]
    float* hfin = out + BATCH * CDIM;          // [B][H]

    // d_ws layout: [hx: 2*B*H f32][flags: B*NSPLIT int, padded][Abuf: rest]
    float* hx = (float*)d_ws;
    const size_t hx_bytes = (size_t)2 * BATCH * HDIM * sizeof(float);   // 128 KB
    int* flags = (int*)((char*)d_ws + hx_bytes);
    const size_t fl_bytes = 512;                                        // >= B*NSPLIT*4
    unsigned short* Abuf = (unsigned short*)((char*)d_ws + hx_bytes + fl_bytes);

    const size_t per_t = (size_t)BATCH * HDIM * sizeof(unsigned short); // 32 KB
    size_t head = hx_bytes + fl_bytes;
    size_t avail = ws_size > head ? ws_size - head : 0;
    long long tcl = (long long)(avail / per_t);
    if (tcl > T_STEPS) tcl = T_STEPS;
    int TC = (int)(tcl & ~3LL);
    if (TC < 4) TC = 4;

    // flags must start at 0 each launch (monotonic within launch)
    hipMemsetAsync(flags, 0, fl_bytes, stream);
    // seed h_0 into exchange buffer parity 0
    hipMemcpyAsync(hx, h0, (size_t)BATCH * HDIM * sizeof(float),
                   hipMemcpyDeviceToDevice, stream);

    for (int t0 = 0; t0 < T_STEPS; t0 += TC) {
        int tc = T_STEPS - t0 < TC ? T_STEPS - t0 : TC;
        xih_gemm<<<dim3(4, tc * BATCH / 128), 256, 0, stream>>>(
            x + (size_t)t0 * BATCH * IDIM, Wih, bih, bhh, Abuf);
        int do_fc = (t0 + tc >= T_STEPS) ? 1 : 0;
        rnn_scan<<<BATCH * NSPLIT, 512, 0, stream>>>(
            Abuf, Whh, Wfc, bfc, hx, flags, out, hfin, tc, t0, do_fc);
    }
}

// Round 8
// 7958.681 us; speedup vs baseline: 8.6934x; 2.2779x over previous
//
#include <hip/hip_runtime.h>
#include <hip/hip_bf16.h>
#include <stdint.h>

#define T_STEPS 4096
#define BATCH 32
#define IDIM 512
#define HDIM 512
#define CDIM 128
#define NSPLIT 4      // blocks per batch (output-dim split)
#define CSLICE 128    // HDIM / NSPLIT
#define QPAD 132      // padded quarter stride in LDS (conflict-free quad reads)

typedef float f32x4 __attribute__((ext_vector_type(4)));
typedef short s16x8 __attribute__((ext_vector_type(8)));
typedef unsigned short u16x4 __attribute__((ext_vector_type(4)));

__device__ __forceinline__ unsigned short f2bf(float f) {
    union { float f; uint32_t u; } v; v.f = f;
    uint32_t r = v.u + 0x7fffu + ((v.u >> 16) & 1u);  // RNE
    return (unsigned short)(r >> 16);
}
__device__ __forceinline__ float bf2f(unsigned short s) {
    union { uint32_t u; float f; } v; v.u = ((uint32_t)s) << 16;
    return v.f;
}

// ---------------------------------------------------------------------------
// Kernel 0: seed exchange buffers.
// buf0 = h0 with mantissa-LSB tag cleared (tag of h_0 is ((0>>1)&1)=0).
// buf1 = dummy with LSB set (consumer of h_1 expects tag 0; 0xAA poison has
// LSB 0 = false-ready, so it MUST be overwritten with tag-1 garbage).
// ---------------------------------------------------------------------------
__global__ void seed_hx(const float* __restrict__ h0, uint32_t* __restrict__ hx) {
    int i = blockIdx.x * 256 + threadIdx.x;
    if (i < BATCH * HDIM) {
        union { float f; uint32_t u; } v; v.f = h0[i];
        hx[i] = v.u & ~1u;                       // buffer 0: h_0, tag 0
        hx[BATCH * HDIM + i] = 0x3f800001u;      // buffer 1: garbage, tag 1
    }
}

// ---------------------------------------------------------------------------
// Kernel 1: A[m][n] = bf16( X[m][:] . Wih[n][:] + bih[n] + bhh[n] )
// ---------------------------------------------------------------------------
__global__ __launch_bounds__(256) void xih_gemm(
    const float* __restrict__ X,    // [M][K] fp32
    const float* __restrict__ Wih,  // [N][K] fp32
    const float* __restrict__ bih,
    const float* __restrict__ bhh,
    unsigned short* __restrict__ A) // [M][N] bf16 bits
{
    __shared__ __align__(16) unsigned short As[128][40];
    __shared__ __align__(16) unsigned short Bs[128][40];

    const int tid  = threadIdx.x;
    const int lane = tid & 63;
    const int wave = tid >> 6;
    const int wr = wave >> 1, wc = wave & 1;
    const int row0 = blockIdx.y * 128;
    const int col0 = blockIdx.x * 128;
    const int l16 = lane & 15, lhi = lane >> 4;

    const int lr = tid >> 3;
    const int kf = tid & 7;

    f32x4 acc[4][4] = {};

    for (int k0 = 0; k0 < IDIM; k0 += 32) {
        #pragma unroll
        for (int rr = 0; rr < 128; rr += 32) {
            int r = lr + rr;
            float4 xv = *(const float4*)&X[(size_t)(row0 + r) * IDIM + k0 + kf * 4];
            float4 wv = *(const float4*)&Wih[(size_t)(col0 + r) * IDIM + k0 + kf * 4];
            u16x4 xq, wq;
            xq.x = f2bf(xv.x); xq.y = f2bf(xv.y); xq.z = f2bf(xv.z); xq.w = f2bf(xv.w);
            wq.x = f2bf(wv.x); wq.y = f2bf(wv.y); wq.z = f2bf(wv.z); wq.w = f2bf(wv.w);
            *(u16x4*)&As[r][kf * 4] = xq;
            *(u16x4*)&Bs[r][kf * 4] = wq;
        }
        __syncthreads();

        s16x8 af[4], bfr[4];
        #pragma unroll
        for (int mi = 0; mi < 4; ++mi)
            af[mi] = *(const s16x8*)&As[wr * 64 + mi * 16 + l16][lhi * 8];
        #pragma unroll
        for (int ni = 0; ni < 4; ++ni)
            bfr[ni] = *(const s16x8*)&Bs[wc * 64 + ni * 16 + l16][lhi * 8];
        #pragma unroll
        for (int mi = 0; mi < 4; ++mi)
            #pragma unroll
            for (int ni = 0; ni < 4; ++ni)
                acc[mi][ni] = __builtin_amdgcn_mfma_f32_16x16x32_bf16(
                    af[mi], bfr[ni], acc[mi][ni], 0, 0, 0);
        __syncthreads();
    }

    #pragma unroll
    for (int ni = 0; ni < 4; ++ni) {
        int col = col0 + wc * 64 + ni * 16 + l16;
        float bias = bih[col] + bhh[col];
        #pragma unroll
        for (int mi = 0; mi < 4; ++mi) {
            int rowb = row0 + wr * 64 + mi * 16 + lhi * 4;
            #pragma unroll
            for (int r = 0; r < 4; ++r)
                A[(size_t)(rowb + r) * HDIM + col] = f2bf(acc[mi][ni][r] + bias);
        }
    }
}

// ---------------------------------------------------------------------------
// Kernel 2: recurrence. 128 blocks (1/CU). W pinned in VGPRs via asm.
// Thread: c = tid>>2 (col), q = tid&3 (k-quarter); quad shfl-reduce.
// Sync: NO flags — freshness tag in mantissa LSB of each h value
// (tag(g) = (g>>1)&1 distinguishes the two uses of each buffer).
// One __syncthreads per step; LDS h staging double-buffered.
// ---------------------------------------------------------------------------
__global__ __launch_bounds__(512, 1) void rnn_scan(
    const unsigned short* __restrict__ A,  // [tc][BATCH][HDIM] bf16 bits
    const float* __restrict__ Whh,         // [HDIM][HDIM] row-major
    const float* __restrict__ Wfc,         // [CDIM][HDIM]
    const float* __restrict__ bfc,         // [CDIM]
    uint32_t* __restrict__ hx,             // [2][BATCH][HDIM] tagged fp32 bits
    float* __restrict__ out,               // [BATCH][CDIM]
    float* __restrict__ hfin,              // [BATCH][HDIM] (2nd output)
    int tc, int t0, int do_fc)
{
    __shared__ __align__(16) float hs[2][4 * QPAD];   // double-buffered staging

    const int tid = threadIdx.x;
    const int b = blockIdx.x >> 2;       // batch
    const int j = blockIdx.x & 3;        // output-slice index
    const int c = tid >> 2;              // local output col 0..127
    const int q = tid & 3;               // k-quarter 0..3
    const int cg = j * CSLICE + c;       // global output col
    const int wq = (tid >> 7) * QPAD + (tid & 127);  // LDS slot for h[tid]

    // ---- W slice in VGPRs: 32 f32x4, pinned with opaque asm ----
    f32x4 w[32];
    {
        const float* wr = Whh + (size_t)cg * HDIM + q * 128;
        #pragma unroll
        for (int i = 0; i < 32; ++i) {
            w[i] = *(const f32x4*)(wr + i * 4);
            asm volatile("" : "+v"(w[i]));   // opaque: cannot be re-loaded
        }
    }

    const unsigned short* Ab = A + (size_t)b * HDIM + cg;
    const uint32_t* hin_base = hx + (size_t)b * HDIM + tid;
    uint32_t* hout_base = hx + (size_t)b * HDIM + cg;

    for (int t = 0; t < tc; ++t) {
        const int gs = t0 + t;           // consume h_gs, produce h_{gs+1}
        const uint32_t exp_tag = (uint32_t)((gs >> 1) & 1);

        // additive term (independent load, issued before the spin)
        float a_t = bf2f(Ab[(size_t)t * (BATCH * HDIM)]);

        // ---- spin directly on my h element (tag = freshness) ----
        const uint32_t* hp = hin_base + (size_t)(gs & 1) * (BATCH * HDIM);
        uint32_t u;
        while (((u = __hip_atomic_load(hp, __ATOMIC_RELAXED,
                                       __HIP_MEMORY_SCOPE_AGENT)) & 1u) != exp_tag) {}
        union { uint32_t u; float f; } hv_in; hv_in.u = u;
        hs[gs & 1][wq] = hv_in.f;        // tag bit kept: <=2^-23 rel error
        __syncthreads();                 // the ONLY barrier per step

        // ---- partial dot: VGPR W x LDS h-quarter ----
        f32x4 acc = {};
        const float* hq = &hs[gs & 1][q * QPAD];
        #pragma unroll
        for (int i = 0; i < 32; ++i) {
            f32x4 hvv = *(const f32x4*)(hq + i * 4);
            acc += w[i] * hvv;
        }
        float v = acc.x + acc.y + acc.z + acc.w;
        v += __shfl_xor(v, 1);
        v += __shfl_xor(v, 2);
        v = fmaxf(v + a_t, 0.f);

        // ---- publish h_{gs+1} with tag((gs+1)) in LSB ----
        if (q == 0) {
            union { float f; uint32_t u; } pv; pv.f = v;
            pv.u = (pv.u & ~1u) | (uint32_t)(((gs + 1) >> 1) & 1);
            uint32_t* ho = hout_base + (size_t)((gs + 1) & 1) * (BATCH * HDIM);
            __hip_atomic_store(ho, pv.u, __ATOMIC_RELAXED,
                               __HIP_MEMORY_SCOPE_AGENT);
            if (do_fc && t == tc - 1)
                hfin[b * HDIM + cg] = v;   // plain store, flushed at kernel end
        }
        // no trailing barrier: LDS double-buffered, spin handles ordering
    }

    // ---- fused FC on final h (block j==0 of each batch) ----
    if (do_fc && j == 0) {
        const int target = t0 + tc;
        const uint32_t exp_tag = (uint32_t)((target >> 1) & 1);
        const uint32_t* hp = hin_base + (size_t)(target & 1) * (BATCH * HDIM);
        uint32_t u;
        while (((u = __hip_atomic_load(hp, __ATOMIC_RELAXED,
                                       __HIP_MEMORY_SCOPE_AGENT)) & 1u) != exp_tag) {}
        union { uint32_t u; float f; } hv_in; hv_in.u = u;
        hs[target & 1][wq] = hv_in.f;
        __syncthreads();

        // out[b][c] = bfc[c] + sum_k Wfc[c][k] * h[k]
        float facc = 0.f;
        const float* wf = Wfc + (size_t)c * HDIM + q * 128;
        const float* hq = &hs[target & 1][q * QPAD];
        #pragma unroll
        for (int i = 0; i < 32; ++i) {
            f32x4 wv = *(const f32x4*)(wf + i * 4);
            f32x4 hvv = *(const f32x4*)(hq + i * 4);
            f32x4 p = wv * hvv;
            facc += p.x + p.y + p.z + p.w;
        }
        facc += __shfl_xor(facc, 1);
        facc += __shfl_xor(facc, 2);
        if (q == 0)
            out[b * CDIM + c] = facc + bfc[c];
    }
}

// ---------------------------------------------------------------------------
extern "C" void kernel_launch(void* const* d_in, const int* in_sizes, int n_in,
                              void* d_out, int out_size, void* d_ws, size_t ws_size,
                              hipStream_t stream) {
    const float* x   = (const float*)d_in[0];  // [T][B][I]
    const float* h0  = (const float*)d_in[1];  // [B][H]
    const float* Wih = (const float*)d_in[2];  // [H][I]
    const float* bih = (const float*)d_in[3];  // [H]
    const float* Whh = (const float*)d_in[4];  // [H][H]
    const float* bhh = (const float*)d_in[5];  // [H]
    const float* Wfc = (const float*)d_in[6];  // [C][H]
    const float* bfc = (const float*)d_in[7];  // [C]

    float* out  = (float*)d_out;               // [B][C]
    float* hfin = out + BATCH * CDIM;          // [B][H]

    // d_ws layout: [hx: 2*B*H u32][Abuf: rest]
    uint32_t* hx = (uint32_t*)d_ws;
    const size_t hx_bytes = (size_t)2 * BATCH * HDIM * sizeof(uint32_t);  // 128 KB
    unsigned short* Abuf = (unsigned short*)((char*)d_ws + hx_bytes);

    const size_t per_t = (size_t)BATCH * HDIM * sizeof(unsigned short);   // 32 KB
    size_t avail = ws_size > hx_bytes ? ws_size - hx_bytes : 0;
    long long tcl = (long long)(avail / per_t);
    if (tcl > T_STEPS) tcl = T_STEPS;
    int TC = (int)(tcl & ~3LL);
    if (TC < 4) TC = 4;

    seed_hx<<<(BATCH * HDIM + 255) / 256, 256, 0, stream>>>(h0, hx);

    for (int t0 = 0; t0 < T_STEPS; t0 += TC) {
        int tc = T_STEPS - t0 < TC ? T_STEPS - t0 : TC;
        xih_gemm<<<dim3(4, tc * BATCH / 128), 256, 0, stream>>>(
            x + (size_t)t0 * BATCH * IDIM, Wih, bih, bhh, Abuf);
        int do_fc = (t0 + tc >= T_STEPS) ? 1 : 0;
        rnn_scan<<<BATCH * NSPLIT, 512, 0, stream>>>(
            Abuf, Whh, Wfc, bfc, hx, out, hfin, tc, t0, do_fc);
    }
}

// Round 10
// 7807.493 us; speedup vs baseline: 8.8617x; 1.0194x over previous
//
#include <hip/hip_runtime.h>
#include <hip/hip_bf16.h>
#include <stdint.h>

#define T_STEPS 4096
#define BATCH 32
#define IDIM 512
#define HDIM 512
#define CDIM 128
#define NSPLIT 8      // blocks per batch (output-dim split)
#define CSLICE 64     // HDIM / NSPLIT
#define QP 68         // padded 64-elem quarter stride (floats): 8 disjoint bank groups

typedef float f32x4 __attribute__((ext_vector_type(4)));
typedef short s16x8 __attribute__((ext_vector_type(8)));
typedef unsigned short u16x4 __attribute__((ext_vector_type(4)));

__device__ __forceinline__ unsigned short f2bf(float f) {
    union { float f; uint32_t u; } v; v.f = f;
    uint32_t r = v.u + 0x7fffu + ((v.u >> 16) & 1u);  // RNE
    return (unsigned short)(r >> 16);
}
__device__ __forceinline__ float bf2f(unsigned short s) {
    union { uint32_t u; float f; } v; v.u = ((uint32_t)s) << 16;
    return v.f;
}

// ---------------------------------------------------------------------------
// Kernel 0: seed exchange buffers.
// buf0 = h0 with mantissa-LSB tag cleared (tag of h_0 = ((0>>1)&1) = 0).
// buf1 = garbage with LSB set (consumers of h_1 expect tag 0; 0xAA poison has
// LSB 0 = false-ready, so buf1 MUST be overwritten with tag-1 garbage).
// ---------------------------------------------------------------------------
__global__ void seed_hx(const float* __restrict__ h0, uint32_t* __restrict__ hx) {
    int i = blockIdx.x * 256 + threadIdx.x;
    if (i < BATCH * HDIM) {
        union { float f; uint32_t u; } v; v.f = h0[i];
        hx[i] = v.u & ~1u;                       // buffer 0: h_0, tag 0
        hx[BATCH * HDIM + i] = 0x3f800001u;      // buffer 1: garbage, tag 1
    }
}

// ---------------------------------------------------------------------------
// Kernel 1: A[m][n] = bf16( X[m][:] . Wih[n][:] + bih[n] + bhh[n] )
// ---------------------------------------------------------------------------
__global__ __launch_bounds__(256) void xih_gemm(
    const float* __restrict__ X,    // [M][K] fp32
    const float* __restrict__ Wih,  // [N][K] fp32
    const float* __restrict__ bih,
    const float* __restrict__ bhh,
    unsigned short* __restrict__ A) // [M][N] bf16 bits
{
    __shared__ __align__(16) unsigned short As[128][40];
    __shared__ __align__(16) unsigned short Bs[128][40];

    const int tid  = threadIdx.x;
    const int lane = tid & 63;
    const int wave = tid >> 6;
    const int wr = wave >> 1, wc = wave & 1;
    const int row0 = blockIdx.y * 128;
    const int col0 = blockIdx.x * 128;
    const int l16 = lane & 15, lhi = lane >> 4;

    const int lr = tid >> 3;
    const int kf = tid & 7;

    f32x4 acc[4][4] = {};

    for (int k0 = 0; k0 < IDIM; k0 += 32) {
        #pragma unroll
        for (int rr = 0; rr < 128; rr += 32) {
            int r = lr + rr;
            float4 xv = *(const float4*)&X[(size_t)(row0 + r) * IDIM + k0 + kf * 4];
            float4 wv = *(const float4*)&Wih[(size_t)(col0 + r) * IDIM + k0 + kf * 4];
            u16x4 xq, wq;
            xq.x = f2bf(xv.x); xq.y = f2bf(xv.y); xq.z = f2bf(xv.z); xq.w = f2bf(xv.w);
            wq.x = f2bf(wv.x); wq.y = f2bf(wv.y); wq.z = f2bf(wv.z); wq.w = f2bf(wv.w);
            *(u16x4*)&As[r][kf * 4] = xq;
            *(u16x4*)&Bs[r][kf * 4] = wq;
        }
        __syncthreads();

        s16x8 af[4], bfr[4];
        #pragma unroll
        for (int mi = 0; mi < 4; ++mi)
            af[mi] = *(const s16x8*)&As[wr * 64 + mi * 16 + l16][lhi * 8];
        #pragma unroll
        for (int ni = 0; ni < 4; ++ni)
            bfr[ni] = *(const s16x8*)&Bs[wc * 64 + ni * 16 + l16][lhi * 8];
        #pragma unroll
        for (int mi = 0; mi < 4; ++mi)
            #pragma unroll
            for (int ni = 0; ni < 4; ++ni)
                acc[mi][ni] = __builtin_amdgcn_mfma_f32_16x16x32_bf16(
                    af[mi], bfr[ni], acc[mi][ni], 0, 0, 0);
        __syncthreads();
    }

    #pragma unroll
    for (int ni = 0; ni < 4; ++ni) {
        int col = col0 + wc * 64 + ni * 16 + l16;
        float bias = bih[col] + bhh[col];
        #pragma unroll
        for (int mi = 0; mi < 4; ++mi) {
            int rowb = row0 + wr * 64 + mi * 16 + lhi * 4;
            #pragma unroll
            for (int r = 0; r < 4; ++r)
                A[(size_t)(rowb + r) * HDIM + col] = f2bf(acc[mi][ni][r] + bias);
        }
    }
}

// ---------------------------------------------------------------------------
// Kernel 2: recurrence. 256 blocks (1/CU), NSPLIT=8 -> 64 cols/block.
// Thread: c = tid>>3 (col 0..63), q = tid&7 (K-eighth, 64 elems).
// W slice = 16 f32x4 = 64 VGPRs -> genuinely register-resident (no spill).
// Sync: mantissa-LSB freshness tag (tag(g) = (g>>1)&1), spin on own element.
// One __syncthreads per step; LDS h staging double-buffered, QP=68 padding
// gives the 8 q-groups disjoint bank quads (zero conflicts).
// ---------------------------------------------------------------------------
__global__ __launch_bounds__(512, 1) void rnn_scan(
    const unsigned short* __restrict__ A,  // [tc][BATCH][HDIM] bf16 bits
    const float* __restrict__ Whh,         // [HDIM][HDIM] row-major
    const float* __restrict__ Wfc,         // [CDIM][HDIM]
    const float* __restrict__ bfc,         // [CDIM]
    uint32_t* __restrict__ hx,             // [2][BATCH][HDIM] tagged fp32 bits
    float* __restrict__ out,               // [BATCH][CDIM]
    float* __restrict__ hfin,              // [BATCH][HDIM] (2nd output)
    int tc, int t0, int do_fc)
{
    __shared__ __align__(16) float hs[2][8 * QP];   // double-buffered staging

    const int tid = threadIdx.x;
    const int b = blockIdx.x >> 3;       // batch
    const int j = blockIdx.x & 7;        // output-slice index
    const int c = tid >> 3;              // local output col 0..63
    const int q = tid & 7;               // k-eighth 0..7
    const int cg = j * CSLICE + c;       // global output col
    const int wq = (tid >> 6) * QP + (tid & 63);  // LDS slot for h[tid]

    // ---- W slice in VGPRs: 16 f32x4, pinned ----
    f32x4 w[16];
    {
        const float* wr = Whh + (size_t)cg * HDIM + q * 64;
        #pragma unroll
        for (int i = 0; i < 16; ++i) {
            w[i] = *(const f32x4*)(wr + i * 4);
            asm volatile("" : "+v"(w[i]));   // opaque: cannot be re-derived
        }
    }

    const unsigned short* Ab = A + (size_t)b * HDIM + cg;
    const uint32_t* hin_base = hx + (size_t)b * HDIM + tid;
    uint32_t* hout_base = hx + (size_t)b * HDIM + cg;

    for (int t = 0; t < tc; ++t) {
        const int gs = t0 + t;           // consume h_gs, produce h_{gs+1}
        const uint32_t exp_tag = (uint32_t)((gs >> 1) & 1);

        // additive term (independent load, overlapped with the spin)
        float a_t = bf2f(Ab[(size_t)t * (BATCH * HDIM)]);

        // ---- spin directly on my h element (tag = freshness) ----
        const uint32_t* hp = hin_base + (size_t)(gs & 1) * (BATCH * HDIM);
        uint32_t u;
        while (((u = __hip_atomic_load(hp, __ATOMIC_RELAXED,
                                       __HIP_MEMORY_SCOPE_AGENT)) & 1u) != exp_tag) {}
        union { uint32_t u; float f; } hv_in; hv_in.u = u;
        hs[gs & 1][wq] = hv_in.f;        // tag bit kept: <=2^-23 rel error
        __syncthreads();                 // the ONLY barrier per step

        // ---- partial dot: VGPR W x LDS h-eighth ----
        f32x4 acc = {};
        const float* hq = &hs[gs & 1][q * QP];
        #pragma unroll
        for (int i = 0; i < 16; ++i) {
            f32x4 hvv = *(const f32x4*)(hq + i * 4);
            acc += w[i] * hvv;
        }
        float v = acc.x + acc.y + acc.z + acc.w;
        v += __shfl_xor(v, 1);
        v += __shfl_xor(v, 2);
        v += __shfl_xor(v, 4);
        v = fmaxf(v + a_t, 0.f);

        // ---- publish h_{gs+1} with tag(gs+1) in LSB ----
        if (q == 0) {
            union { float f; uint32_t u; } pv; pv.f = v;
            pv.u = (pv.u & ~1u) | (uint32_t)(((gs + 1) >> 1) & 1);
            uint32_t* ho = hout_base + (size_t)((gs + 1) & 1) * (BATCH * HDIM);
            __hip_atomic_store(ho, pv.u, __ATOMIC_RELAXED,
                               __HIP_MEMORY_SCOPE_AGENT);
            if (do_fc && t == tc - 1)
                hfin[b * HDIM + cg] = v;   // plain store, flushed at kernel end
        }
        // no trailing barrier: LDS double-buffered, spin handles ordering
    }

    // ---- fused FC on final h (block j==0 of each batch) ----
    if (do_fc && j == 0) {
        const int target = t0 + tc;
        const uint32_t exp_tag = (uint32_t)((target >> 1) & 1);
        const uint32_t* hp = hin_base + (size_t)(target & 1) * (BATCH * HDIM);
        uint32_t u;
        while (((u = __hip_atomic_load(hp, __ATOMIC_RELAXED,
                                       __HIP_MEMORY_SCOPE_AGENT)) & 1u) != exp_tag) {}
        union { uint32_t u; float f; } hv_in; hv_in.u = u;
        hs[target & 1][wq] = hv_in.f;
        __syncthreads();

        // out[b][c2] = bfc[c2] + sum_k Wfc[c2][k] * h[k]; c2 = tid>>2, q2 = tid&3
        const int c2 = tid >> 2;
        const int q2 = tid & 3;
        float facc = 0.f;
        const float* wf = Wfc + (size_t)c2 * HDIM + q2 * 128;
        const float* hb2 = hs[target & 1];
        #pragma unroll
        for (int i = 0; i < 32; ++i) {
            int e = q2 * 128 + i * 4;                       // logical h element
            f32x4 hvv = *(const f32x4*)(hb2 + (e >> 6) * QP + (e & 63));
            f32x4 wv = *(const f32x4*)(wf + i * 4);
            f32x4 p = wv * hvv;
            facc += p.x + p.y + p.z + p.w;
        }
        facc += __shfl_xor(facc, 1);
        facc += __shfl_xor(facc, 2);
        if (q2 == 0)
            out[b * CDIM + c2] = facc + bfc[c2];
    }
}

// ---------------------------------------------------------------------------
extern "C" void kernel_launch(void* const* d_in, const int* in_sizes, int n_in,
                              void* d_out, int out_size, void* d_ws, size_t ws_size,
                              hipStream_t stream) {
    const float* x   = (const float*)d_in[0];  // [T][B][I]
    const float* h0  = (const float*)d_in[1];  // [B][H]
    const float* Wih = (const float*)d_in[2];  // [H][I]
    const float* bih = (const float*)d_in[3];  // [H]
    const float* Whh = (const float*)d_in[4];  // [H][H]
    const float* bhh = (const float*)d_in[5];  // [H]
    const float* Wfc = (const float*)d_in[6];  // [C][H]
    const float* bfc = (const float*)d_in[7];  // [C]

    float* out  = (float*)d_out;               // [B][C]
    float* hfin = out + BATCH * CDIM;          // [B][H]

    // d_ws layout: [hx: 2*B*H u32][Abuf: rest]
    uint32_t* hx = (uint32_t*)d_ws;
    const size_t hx_bytes = (size_t)2 * BATCH * HDIM * sizeof(uint32_t);  // 128 KB
    unsigned short* Abuf = (unsigned short*)((char*)d_ws + hx_bytes);

    const size_t per_t = (size_t)BATCH * HDIM * sizeof(unsigned short);   // 32 KB
    size_t avail = ws_size > hx_bytes ? ws_size - hx_bytes : 0;
    long long tcl = (long long)(avail / per_t);
    if (tcl > T_STEPS) tcl = T_STEPS;
    int TC = (int)(tcl & ~3LL);
    if (TC < 4) TC = 4;

    seed_hx<<<(BATCH * HDIM + 255) / 256, 256, 0, stream>>>(h0, hx);

    for (int t0 = 0; t0 < T_STEPS; t0 += TC) {
        int tc = T_STEPS - t0 < TC ? T_STEPS - t0 : TC;
        xih_gemm<<<dim3(4, tc * BATCH / 128), 256, 0, stream>>>(
            x + (size_t)t0 * BATCH * IDIM, Wih, bih, bhh, Abuf);
        int do_fc = (t0 + tc >= T_STEPS) ? 1 : 0;
        rnn_scan<<<BATCH * NSPLIT, 512, 0, stream>>>(
            Abuf, Whh, Wfc, bfc, hx, out, hfin, tc, t0, do_fc);
    }
}